// Round 14
// baseline (250.509 us; speedup 1.0000x reference)
//
#include <hip/hip_runtime.h>
#include <hip/hip_bf16.h>

#define N_NODES 10000
#define N_EDGES 160000
#define F_IN    128
#define F_OUT   128
#define BATCH   8
#define NROWS   (BATCH * N_NODES)   // 80000
#define TN      64                  // nodes per fused block (one batch)
#define NTILES  ((N_NODES + TN - 1) / TN)   // 157

// ---------------- OLD (fallback) workspace layout ----------------
#define WS_FLAG_OFF   0
#define WS_WT_OFF     256
#define WS_DEG_OFF    131328
#define WS_ROW_OFF    171328
#define WS_CUR_OFF    211332
#define WS_COL_OFF    251332
#define WS_TOTAL      891332

// ---------------- bf16 workspace layout ----------------
#define WS2_FLAG  0
#define WS2_WT    256          // bf16 Wcat [128][256] = 65536
#define WS2_DEG   65792       // 40000
#define WS2_ROW   105792      // 40004
#define WS2_CUR   145796      // 40000
#define WS2_COL   185796      // 640000
#define WS2_XH    825856      // 8*10000*128*2 = 20480000
#define WS2_NEED  21305856    // end of xh

typedef __attribute__((ext_vector_type(8))) short short8;
typedef __attribute__((ext_vector_type(4))) float floatx4;

__device__ __forceinline__ int edge_val(const void* ei, int idx, int i64) {
    if (i64) return (int)((const long long*)ei)[idx];
    return ((const int*)ei)[idx];
}

__global__ void detect_i64_kernel(const void* ei, int* flag) {
    __shared__ int any_nonzero;
    if (threadIdx.x == 0) any_nonzero = 0;
    __syncthreads();
    int v = ((const int*)ei)[2 * threadIdx.x + 1];
    if (v != 0) atomicOr(&any_nonzero, 1);
    __syncthreads();
    if (threadIdx.x == 0) *flag = (any_nonzero == 0) ? 1 : 0;
}

__global__ void hist_kernel(const void* ei, const int* __restrict__ flag,
                            int* __restrict__ deg) {
    int e = blockIdx.x * 256 + threadIdx.x;
    if (e >= N_EDGES) return;
    int i64 = *flag;
    int d = edge_val(ei, N_EDGES + e, i64);
    atomicAdd(&deg[d], 1);
}

__global__ __launch_bounds__(1024)
void scan_kernel(const int* __restrict__ deg, int* __restrict__ row_start) {
    __shared__ int sd[1024];
    const int CH = (N_NODES + 1023) / 1024;   // 10
    int t = threadIdx.x;
    int beg = t * CH;
    int end = min(N_NODES, beg + CH);
    int s = 0;
    for (int i = beg; i < end; i++) s += deg[i];
    sd[t] = s;
    __syncthreads();
    for (int off = 1; off < 1024; off <<= 1) {
        int v = (t >= off) ? sd[t - off] : 0;
        __syncthreads();
        sd[t] += v;
        __syncthreads();
    }
    int run = sd[t] - s;   // exclusive prefix
    for (int i = beg; i < end; i++) { row_start[i] = run; run += deg[i]; }
    if (t == 1023) row_start[N_NODES] = sd[1023];
}

__global__ void scatter_kernel(const void* ei, const int* __restrict__ flag,
                               const int* __restrict__ row_start,
                               int* __restrict__ cursor, int* __restrict__ col) {
    int e = blockIdx.x * 256 + threadIdx.x;
    if (e >= N_EDGES) return;
    int i64 = *flag;
    int s = edge_val(ei, e, i64);
    int d = edge_val(ei, N_EDGES + e, i64);
    int pos = atomicAdd(&cursor[d], 1);
    col[row_start[d] + pos] = s;
}

// ======================= bf16 helpers =======================

__device__ __forceinline__ unsigned short f2bf(float v) {
    __hip_bfloat16 h = __float2bfloat16(v);
    return *(unsigned short*)&h;
}

__device__ __forceinline__ uint2 pack4(float4 v) {
    uint2 r;
    r.x = (unsigned)f2bf(v.x) | ((unsigned)f2bf(v.y) << 16);
    r.y = (unsigned)f2bf(v.z) | ((unsigned)f2bf(v.w) << 16);
    return r;
}

__device__ __forceinline__ void acc4(float4& a, uint2 p) {
    a.x += __uint_as_float(p.x << 16);
    a.y += __uint_as_float(p.x & 0xffff0000u);
    a.z += __uint_as_float(p.y << 16);
    a.w += __uint_as_float(p.y & 0xffff0000u);
}

// Wcat_bf16[o][k]: k<128 -> W_l[o][k], else W_r[o][k-128]
__global__ void make_wt_bf16(const float* __restrict__ Wl,
                             const float* __restrict__ Wr,
                             unsigned short* __restrict__ Wt) {
    int idx = blockIdx.x * 256 + threadIdx.x;   // 0..32767
    int o = idx >> 8;
    int k = idx & 255;
    float v = (k < F_IN) ? Wl[o * F_IN + k] : Wr[o * F_IN + (k - F_IN)];
    Wt[idx] = f2bf(v);
}

// x (fp32) -> xh (bf16)
__global__ __launch_bounds__(256)
void convert_kernel(const float* __restrict__ x, uint2* __restrict__ xh2) {
    int t = blockIdx.x * 256 + threadIdx.x;     // 0..2559999
    float4 v = ((const float4*)x)[t];
    xh2[t] = pack4(v);
}

// ============ fused gather + MFMA GEMM, batch-per-XCD ============
// One block = 64 nodes x ONE batch (batch = blockIdx & 7 -> XCD affinity:
// each batch's 2.56 MB xh slab fits a single XCD's 4 MB L2).
// Phase A: thread (g = t>>5, c = t&31) gathers means for rows r = ni*8+g,
//          writing [mean;self] into the XOR-swizzled 64x256 bf16 LDS tile.
// Phase B: 4 waves x 16-row sub-tiles, 64x MFMA 16x16x32; rows map to
//          out[b*N + n0 + r], guarded for the tail tile.
__global__ __launch_bounds__(256)
void sage_fused_mfma(const uint2* __restrict__ xh2,
                     const int* __restrict__ row_start,
                     const int* __restrict__ col,
                     const unsigned short* __restrict__ Wt,
                     const float* __restrict__ bl,
                     float* __restrict__ out) {
    __shared__ unsigned short Z[64 * 256];   // 32 KB, 64 rows x 512 B swizzled

    const int b    = blockIdx.x & 7;          // batch == XCD (round-robin)
    const int tile = blockIdx.x >> 3;
    const int n0   = tile * TN;
    const int t    = threadIdx.x;
    const int g    = t >> 5;                  // row group 0..7
    const int c    = t & 31;                  // 8B chunk 0..31

    const size_t bbase = (size_t)b * N_NODES;

    #pragma unroll 2
    for (int ni = 0; ni < 8; ++ni) {
        const int r = ni * 8 + g;             // LDS row 0..63
        const int n = n0 + r;
        int beg = 0, end = 0;
        if (n < N_NODES) { beg = row_start[n]; end = row_start[n + 1]; }
        const int d = end - beg;

        float4 s0 = make_float4(0.f,0.f,0.f,0.f), s1 = s0, s2 = s0, s3 = s0;
        int i = beg;
        for (; i + 4 <= end; i += 4) {
            int m0 = col[i], m1 = col[i+1], m2 = col[i+2], m3 = col[i+3];
            acc4(s0, xh2[(bbase + m0) * 32 + c]);
            acc4(s1, xh2[(bbase + m1) * 32 + c]);
            acc4(s2, xh2[(bbase + m2) * 32 + c]);
            acc4(s3, xh2[(bbase + m3) * 32 + c]);
        }
        for (; i < end; ++i) acc4(s0, xh2[(bbase + col[i]) * 32 + c]);

        s0.x += s1.x + s2.x + s3.x; s0.y += s1.y + s2.y + s3.y;
        s0.z += s1.z + s2.z + s3.z; s0.w += s1.w + s2.w + s3.w;
        const float inv = 1.0f / (float)max(d, 1);
        uint2 mp = pack4(make_float4(s0.x*inv, s0.y*inv, s0.z*inv, s0.w*inv));
        uint2 sp = (n < N_NODES) ? xh2[(bbase + n) * 32 + c]
                                 : make_uint2(0u, 0u);

        const int sub = (c & 1) * 8;         // 8B offset within 16B chunk
        const int cc0 = c >> 1;              // mean: chunks 0..15
        const int cc1 = 16 + (c >> 1);       // self: chunks 16..31
        *(uint2*)((char*)Z + r * 512 + ((cc0 ^ (r & 7)) * 16) + sub) = mp;
        *(uint2*)((char*)Z + r * 512 + ((cc1 ^ (r & 7)) * 16) + sub) = sp;
    }
    __syncthreads();

    // Phase B
    const int w  = t >> 6;    // wave 0..3 -> rows w*16..w*16+15
    const int l  = t & 63;
    const int lr = l & 15;
    const int kg = l >> 4;    // 0..3

    floatx4 acc[8];
    #pragma unroll
    for (int j = 0; j < 8; ++j) acc[j] = (floatx4){0.f, 0.f, 0.f, 0.f};

    #pragma unroll
    for (int ks = 0; ks < 8; ++ks) {
        const int r   = w * 16 + lr;
        const int cch = ks * 4 + kg;
        short8 af = *(const short8*)((const char*)Z + r * 512 + ((cch ^ (r & 7)) * 16));
        #pragma unroll
        for (int jt = 0; jt < 8; ++jt) {
            short8 bf = *(const short8*)(Wt + (size_t)(jt * 16 + lr) * 256 + ks * 32 + kg * 8);
            acc[jt] = __builtin_amdgcn_mfma_f32_16x16x32_bf16(af, bf, acc[jt], 0, 0, 0);
        }
    }

    #pragma unroll
    for (int jt = 0; jt < 8; ++jt) {
        const int colo = jt * 16 + lr;
        const float bias = bl[colo];
        const int rt = w * 16 + kg * 4;
        #pragma unroll
        for (int q = 0; q < 4; ++q) {
            const int r = rt + q;
            const int n = n0 + r;
            if (n < N_NODES) {
                out[((size_t)b * N_NODES + n) * F_OUT + colo] = acc[jt][q] + bias;
            }
        }
    }
}

// ======================= OLD fp32 fallback path =======================

__global__ void transpose_w_kernel(const float* __restrict__ Wl,
                                   const float* __restrict__ Wr,
                                   float* __restrict__ Wt) {
    int idx = blockIdx.x * 256 + threadIdx.x;
    int f = idx >> 7;
    int o = idx & 127;
    float v = (f < F_IN) ? Wl[o * F_IN + f] : Wr[o * F_IN + (f - F_IN)];
    Wt[f * F_OUT + o] = v;
}

__global__ __launch_bounds__(256)
void sage_fused_kernel(const float* __restrict__ x,
                       const float* __restrict__ bl,
                       const float* __restrict__ Wt,
                       const int* __restrict__ row_start,
                       const int* __restrict__ col,
                       float* __restrict__ out) {
    __shared__ float in_lds[BATCH][2 * F_IN];

    const int n = blockIdx.x;
    const int t = threadIdx.x;
    const int b = t >> 5;
    const int c = t & 31;

    const int beg = row_start[n];
    const int end = row_start[n + 1];

    const float* xb = x + (size_t)b * N_NODES * F_IN;

    float4 acc = make_float4(0.f, 0.f, 0.f, 0.f);
    for (int i = beg; i < end; i++) {
        int s = col[i];
        const float4 v = *(const float4*)(xb + (size_t)s * F_IN + c * 4);
        acc.x += v.x; acc.y += v.y; acc.z += v.z; acc.w += v.w;
    }
    const float inv = 1.0f / (float)max(end - beg, 1);
    const float4 self = *(const float4*)(xb + (size_t)n * F_IN + c * 4);

    *(float4*)&in_lds[b][c * 4] =
        make_float4(acc.x * inv, acc.y * inv, acc.z * inv, acc.w * inv);
    *(float4*)&in_lds[b][F_IN + c * 4] = self;
    __syncthreads();

    float4 oacc = *(const float4*)(bl + c * 4);
    #pragma unroll 8
    for (int f4 = 0; f4 < 64; f4++) {
        const float4 inq = *(const float4*)&in_lds[b][f4 * 4];
        const float4 w0 = *(const float4*)(Wt + (f4 * 4 + 0) * F_OUT + c * 4);
        const float4 w1 = *(const float4*)(Wt + (f4 * 4 + 1) * F_OUT + c * 4);
        const float4 w2 = *(const float4*)(Wt + (f4 * 4 + 2) * F_OUT + c * 4);
        const float4 w3 = *(const float4*)(Wt + (f4 * 4 + 3) * F_OUT + c * 4);
        oacc.x += inq.x * w0.x; oacc.y += inq.x * w0.y; oacc.z += inq.x * w0.z; oacc.w += inq.x * w0.w;
        oacc.x += inq.y * w1.x; oacc.y += inq.y * w1.y; oacc.z += inq.y * w1.z; oacc.w += inq.y * w1.w;
        oacc.x += inq.z * w2.x; oacc.y += inq.z * w2.y; oacc.z += inq.z * w2.z; oacc.w += inq.z * w2.w;
        oacc.x += inq.w * w3.x; oacc.y += inq.w * w3.y; oacc.z += inq.w * w3.z; oacc.w += inq.w * w3.w;
    }

    *(float4*)(out + ((size_t)b * N_NODES + n) * F_OUT + c * 4) = oacc;
}

extern "C" void kernel_launch(void* const* d_in, const int* in_sizes, int n_in,
                              void* d_out, int out_size, void* d_ws, size_t ws_size,
                              hipStream_t stream) {
    const float* x  = (const float*)d_in[0];
    const float* Wl = (const float*)d_in[1];
    const float* bl = (const float*)d_in[2];
    const float* Wr = (const float*)d_in[3];
    const void*  ei = d_in[4];
    float* out = (float*)d_out;
    char* ws = (char*)d_ws;

    if (ws_size >= (size_t)WS2_NEED + 1024) {
        int*            flag = (int*)(ws + WS2_FLAG);
        unsigned short* Wt   = (unsigned short*)(ws + WS2_WT);
        int*            deg  = (int*)(ws + WS2_DEG);
        int*            rowp = (int*)(ws + WS2_ROW);
        int*            cur  = (int*)(ws + WS2_CUR);
        int*            col  = (int*)(ws + WS2_COL);
        uint2*          xh2  = (uint2*)(ws + WS2_XH);

        hipMemsetAsync(ws + WS2_DEG, 0, WS2_COL - WS2_DEG, stream);
        detect_i64_kernel<<<1, 256, 0, stream>>>(ei, flag);
        make_wt_bf16<<<128, 256, 0, stream>>>(Wl, Wr, Wt);
        hist_kernel<<<(N_EDGES + 255) / 256, 256, 0, stream>>>(ei, flag, deg);
        scan_kernel<<<1, 1024, 0, stream>>>(deg, rowp);
        scatter_kernel<<<(N_EDGES + 255) / 256, 256, 0, stream>>>(ei, flag, rowp, cur, col);
        convert_kernel<<<(NROWS * 32) / 256, 256, 0, stream>>>(x, xh2);
        sage_fused_mfma<<<NTILES * BATCH, 256, 0, stream>>>(xh2, rowp, col, Wt, bl, out);
    } else {
        int*   flag      = (int*)(ws + WS_FLAG_OFF);
        float* Wt        = (float*)(ws + WS_WT_OFF);
        int*   deg       = (int*)(ws + WS_DEG_OFF);
        int*   row_start = (int*)(ws + WS_ROW_OFF);
        int*   cursor    = (int*)(ws + WS_CUR_OFF);
        int*   col       = (int*)(ws + WS_COL_OFF);

        hipMemsetAsync(d_ws, 0, WS_TOTAL, stream);
        detect_i64_kernel<<<1, 256, 0, stream>>>(ei, flag);
        transpose_w_kernel<<<(256 * 128) / 256, 256, 0, stream>>>(Wl, Wr, Wt);
        hist_kernel<<<(N_EDGES + 255) / 256, 256, 0, stream>>>(ei, flag, deg);
        scan_kernel<<<1, 1024, 0, stream>>>(deg, row_start);
        scatter_kernel<<<(N_EDGES + 255) / 256, 256, 0, stream>>>(ei, flag, row_start, cursor, col);
        sage_fused_kernel<<<N_NODES, 256, 0, stream>>>(x, bl, Wt, row_start, col, out);
    }
}

// Round 15
// 204.957 us; speedup vs baseline: 1.2223x; 1.2223x over previous
//
#include <hip/hip_runtime.h>
#include <hip/hip_bf16.h>

#define N_NODES 10000
#define N_EDGES 160000
#define F_IN    128
#define F_OUT   128
#define BATCH   8
#define NROWS   (BATCH * N_NODES)   // 80000

// ---------------- OLD (fallback) workspace layout ----------------
#define WS_FLAG_OFF   0
#define WS_WT_OFF     256
#define WS_DEG_OFF    131328
#define WS_ROW_OFF    171328
#define WS_CUR_OFF    211332
#define WS_COL_OFF    251332
#define WS_TOTAL      891332

// ---------------- bf16 workspace layout ----------------
#define WS2_FLAG  0
#define WS2_WT    256          // bf16 Wcat [128][256] = 65536
#define WS2_DEG   65792       // 40000
#define WS2_ROW   105792      // 40004
#define WS2_CUR   145796      // 40000
#define WS2_COL   185796      // 640000
#define WS2_XH    825856      // 8*10000*128*2 = 20480000
#define WS2_NEED  21305856    // end of xh

typedef __attribute__((ext_vector_type(8))) short short8;
typedef __attribute__((ext_vector_type(4))) float floatx4;

__device__ __forceinline__ int edge_val(const void* ei, int idx, int i64) {
    if (i64) return (int)((const long long*)ei)[idx];
    return ((const int*)ei)[idx];
}

__global__ void detect_i64_kernel(const void* ei, int* flag) {
    __shared__ int any_nonzero;
    if (threadIdx.x == 0) any_nonzero = 0;
    __syncthreads();
    int v = ((const int*)ei)[2 * threadIdx.x + 1];
    if (v != 0) atomicOr(&any_nonzero, 1);
    __syncthreads();
    if (threadIdx.x == 0) *flag = (any_nonzero == 0) ? 1 : 0;
}

__global__ void hist_kernel(const void* ei, const int* __restrict__ flag,
                            int* __restrict__ deg) {
    int e = blockIdx.x * 256 + threadIdx.x;
    if (e >= N_EDGES) return;
    int i64 = *flag;
    int d = edge_val(ei, N_EDGES + e, i64);
    atomicAdd(&deg[d], 1);
}

__global__ __launch_bounds__(1024)
void scan_kernel(const int* __restrict__ deg, int* __restrict__ row_start) {
    __shared__ int sd[1024];
    const int CH = (N_NODES + 1023) / 1024;   // 10
    int t = threadIdx.x;
    int beg = t * CH;
    int end = min(N_NODES, beg + CH);
    int s = 0;
    for (int i = beg; i < end; i++) s += deg[i];
    sd[t] = s;
    __syncthreads();
    for (int off = 1; off < 1024; off <<= 1) {
        int v = (t >= off) ? sd[t - off] : 0;
        __syncthreads();
        sd[t] += v;
        __syncthreads();
    }
    int run = sd[t] - s;   // exclusive prefix
    for (int i = beg; i < end; i++) { row_start[i] = run; run += deg[i]; }
    if (t == 1023) row_start[N_NODES] = sd[1023];
}

__global__ void scatter_kernel(const void* ei, const int* __restrict__ flag,
                               const int* __restrict__ row_start,
                               int* __restrict__ cursor, int* __restrict__ col) {
    int e = blockIdx.x * 256 + threadIdx.x;
    if (e >= N_EDGES) return;
    int i64 = *flag;
    int s = edge_val(ei, e, i64);
    int d = edge_val(ei, N_EDGES + e, i64);
    int pos = atomicAdd(&cursor[d], 1);
    col[row_start[d] + pos] = s;
}

// ======================= bf16 helpers =======================

__device__ __forceinline__ unsigned short f2bf(float v) {
    __hip_bfloat16 h = __float2bfloat16(v);
    return *(unsigned short*)&h;
}

__device__ __forceinline__ uint2 pack4(float4 v) {
    uint2 r;
    r.x = (unsigned)f2bf(v.x) | ((unsigned)f2bf(v.y) << 16);
    r.y = (unsigned)f2bf(v.z) | ((unsigned)f2bf(v.w) << 16);
    return r;
}

__device__ __forceinline__ void acc4(float4& a, uint2 p) {
    a.x += __uint_as_float(p.x << 16);
    a.y += __uint_as_float(p.x & 0xffff0000u);
    a.z += __uint_as_float(p.y << 16);
    a.w += __uint_as_float(p.y & 0xffff0000u);
}

// Wcat_bf16[o][k]: k<128 -> W_l[o][k], else W_r[o][k-128]
__global__ void make_wt_bf16(const float* __restrict__ Wl,
                             const float* __restrict__ Wr,
                             unsigned short* __restrict__ Wt) {
    int idx = blockIdx.x * 256 + threadIdx.x;   // 0..32767
    int o = idx >> 8;
    int k = idx & 255;
    float v = (k < F_IN) ? Wl[o * F_IN + k] : Wr[o * F_IN + (k - F_IN)];
    Wt[idx] = f2bf(v);
}

// x (fp32) -> xh (bf16)
__global__ __launch_bounds__(256)
void convert_kernel(const float* __restrict__ x, uint2* __restrict__ xh2) {
    int t = blockIdx.x * 256 + threadIdx.x;     // 0..2559999
    float4 v = ((const float4*)x)[t];
    xh2[t] = pack4(v);
}

// ============ fused gather + MFMA, 2 nodes x 8 batches per block ============
// 256 threads: (ni = t>>7, bq = (t>>5)&3, c = t&31). Each thread gathers one
// node's mean for TWO batches (bq, bq+4), chunk c — 8 loads in flight.
// Edge lists staged in LDS (wave-uniform, off the critical path).
// LDS tile: 16 rows (r = b*2+ni) x 256 bf16, XOR-swizzled. Phase B: single
// M=16 tile, 4 waves x 2 N-tiles x 8 K-steps of mfma_16x16x32_bf16.
__global__ __launch_bounds__(256)
void sage_fused2(const uint2* __restrict__ xh2,
                 const int* __restrict__ row_start,
                 const int* __restrict__ col,
                 const unsigned short* __restrict__ Wt,
                 const float* __restrict__ bl,
                 float* __restrict__ out) {
    __shared__ unsigned short Z[16 * 256];   // 8 KB
    __shared__ int nbr[2][1024];             // 8 KB

    const int n0 = blockIdx.x * 2;
    const int t  = threadIdx.x;
    const int ni = t >> 7;          // node slot 0/1
    const int bq = (t >> 5) & 3;    // batch quarter 0..3 -> batches bq, bq+4
    const int c  = t & 31;          // 8B chunk

    const int b0 = row_start[n0];
    const int e0 = row_start[n0 + 1];
    const int e1 = row_start[n0 + 2];
    const int cnt0 = min(e0 - b0, 1024);
    const int cnt1 = min(e1 - e0, 1024);
    for (int i = t; i < cnt0; i += 256) nbr[0][i] = col[b0 + i];
    for (int i = t; i < cnt1; i += 256) nbr[1][i] = col[e0 + i];
    __syncthreads();

    const int n   = n0 + ni;
    const int beg = ni ? e0 : b0;
    const int end = ni ? e1 : e0;
    const int d   = end - beg;
    const int cnt = ni ? cnt1 : cnt0;
    const int* nb = nbr[ni];

    const size_t baseA = (size_t)bq * N_NODES;        // batch bq
    const size_t baseB = (size_t)(bq + 4) * N_NODES;  // batch bq+4

    float4 sA0 = make_float4(0.f,0.f,0.f,0.f), sA1 = sA0, sA2 = sA0, sA3 = sA0;
    float4 sB0 = sA0, sB1 = sA0, sB2 = sA0, sB3 = sA0;
    int i = 0;
    for (; i + 4 <= cnt; i += 4) {
        int m0 = nb[i], m1 = nb[i+1], m2 = nb[i+2], m3 = nb[i+3];
        acc4(sA0, xh2[(baseA + m0) * 32 + c]);
        acc4(sB0, xh2[(baseB + m0) * 32 + c]);
        acc4(sA1, xh2[(baseA + m1) * 32 + c]);
        acc4(sB1, xh2[(baseB + m1) * 32 + c]);
        acc4(sA2, xh2[(baseA + m2) * 32 + c]);
        acc4(sB2, xh2[(baseB + m2) * 32 + c]);
        acc4(sA3, xh2[(baseA + m3) * 32 + c]);
        acc4(sB3, xh2[(baseB + m3) * 32 + c]);
    }
    for (; i < cnt; ++i) {
        int m = nb[i];
        acc4(sA0, xh2[(baseA + m) * 32 + c]);
        acc4(sB0, xh2[(baseB + m) * 32 + c]);
    }
    for (int j = 1024; j < d; ++j) {   // pathological-degree fallback
        int m = col[beg + j];
        acc4(sA0, xh2[(baseA + m) * 32 + c]);
        acc4(sB0, xh2[(baseB + m) * 32 + c]);
    }
    sA0.x += sA1.x + sA2.x + sA3.x; sA0.y += sA1.y + sA2.y + sA3.y;
    sA0.z += sA1.z + sA2.z + sA3.z; sA0.w += sA1.w + sA2.w + sA3.w;
    sB0.x += sB1.x + sB2.x + sB3.x; sB0.y += sB1.y + sB2.y + sB3.y;
    sB0.z += sB1.z + sB2.z + sB3.z; sB0.w += sB1.w + sB2.w + sB3.w;

    const float inv = 1.0f / (float)max(d, 1);
    uint2 mpA = pack4(make_float4(sA0.x*inv, sA0.y*inv, sA0.z*inv, sA0.w*inv));
    uint2 mpB = pack4(make_float4(sB0.x*inv, sB0.y*inv, sB0.z*inv, sB0.w*inv));
    uint2 spA = xh2[(baseA + n) * 32 + c];
    uint2 spB = xh2[(baseB + n) * 32 + c];

    const int rA  = bq * 2 + ni;          // rows 0..7
    const int rB  = (bq + 4) * 2 + ni;    // rows 8..15
    const int sub = (c & 1) * 8;
    const int cc0 = c >> 1;               // mean: chunks 0..15
    const int cc1 = 16 + (c >> 1);        // self: chunks 16..31
    *(uint2*)((char*)Z + rA * 512 + ((cc0 ^ (rA & 7)) * 16) + sub) = mpA;
    *(uint2*)((char*)Z + rA * 512 + ((cc1 ^ (rA & 7)) * 16) + sub) = spA;
    *(uint2*)((char*)Z + rB * 512 + ((cc0 ^ (rB & 7)) * 16) + sub) = mpB;
    *(uint2*)((char*)Z + rB * 512 + ((cc1 ^ (rB & 7)) * 16) + sub) = spB;
    __syncthreads();

    // Phase B: one M=16 tile; wave w computes N-tiles jt = w*2, w*2+1
    const int w  = t >> 6;
    const int l  = t & 63;
    const int lr = l & 15;
    const int kg = l >> 4;    // 0..3

    floatx4 acc0 = (floatx4){0.f, 0.f, 0.f, 0.f};
    floatx4 acc1 = (floatx4){0.f, 0.f, 0.f, 0.f};

    #pragma unroll
    for (int ks = 0; ks < 8; ++ks) {
        const int cch = ks * 4 + kg;
        short8 af = *(const short8*)((const char*)Z + lr * 512 + ((cch ^ (lr & 7)) * 16));
        short8 bf0 = *(const short8*)(Wt + (size_t)((w * 2 + 0) * 16 + lr) * 256 + ks * 32 + kg * 8);
        short8 bf1 = *(const short8*)(Wt + (size_t)((w * 2 + 1) * 16 + lr) * 256 + ks * 32 + kg * 8);
        acc0 = __builtin_amdgcn_mfma_f32_16x16x32_bf16(af, bf0, acc0, 0, 0, 0);
        acc1 = __builtin_amdgcn_mfma_f32_16x16x32_bf16(af, bf1, acc1, 0, 0, 0);
    }

    #pragma unroll
    for (int jt2 = 0; jt2 < 2; ++jt2) {
        const int colo = (w * 2 + jt2) * 16 + lr;
        const float bias = bl[colo];
        const floatx4 a = jt2 ? acc1 : acc0;
        #pragma unroll
        for (int q = 0; q < 4; ++q) {
            const int r = kg * 4 + q;          // 0..15
            const int b = r >> 1;
            const int nn = n0 + (r & 1);
            out[((size_t)b * N_NODES + nn) * F_OUT + colo] = a[q] + bias;
        }
    }
}

// ======================= OLD fp32 fallback path =======================

__global__ void transpose_w_kernel(const float* __restrict__ Wl,
                                   const float* __restrict__ Wr,
                                   float* __restrict__ Wt) {
    int idx = blockIdx.x * 256 + threadIdx.x;
    int f = idx >> 7;
    int o = idx & 127;
    float v = (f < F_IN) ? Wl[o * F_IN + f] : Wr[o * F_IN + (f - F_IN)];
    Wt[f * F_OUT + o] = v;
}

__global__ __launch_bounds__(256)
void sage_fused_kernel(const float* __restrict__ x,
                       const float* __restrict__ bl,
                       const float* __restrict__ Wt,
                       const int* __restrict__ row_start,
                       const int* __restrict__ col,
                       float* __restrict__ out) {
    __shared__ float in_lds[BATCH][2 * F_IN];

    const int n = blockIdx.x;
    const int t = threadIdx.x;
    const int b = t >> 5;
    const int c = t & 31;

    const int beg = row_start[n];
    const int end = row_start[n + 1];

    const float* xb = x + (size_t)b * N_NODES * F_IN;

    float4 acc = make_float4(0.f, 0.f, 0.f, 0.f);
    for (int i = beg; i < end; i++) {
        int s = col[i];
        const float4 v = *(const float4*)(xb + (size_t)s * F_IN + c * 4);
        acc.x += v.x; acc.y += v.y; acc.z += v.z; acc.w += v.w;
    }
    const float inv = 1.0f / (float)max(end - beg, 1);
    const float4 self = *(const float4*)(xb + (size_t)n * F_IN + c * 4);

    *(float4*)&in_lds[b][c * 4] =
        make_float4(acc.x * inv, acc.y * inv, acc.z * inv, acc.w * inv);
    *(float4*)&in_lds[b][F_IN + c * 4] = self;
    __syncthreads();

    float4 oacc = *(const float4*)(bl + c * 4);
    #pragma unroll 8
    for (int f4 = 0; f4 < 64; f4++) {
        const float4 inq = *(const float4*)&in_lds[b][f4 * 4];
        const float4 w0 = *(const float4*)(Wt + (f4 * 4 + 0) * F_OUT + c * 4);
        const float4 w1 = *(const float4*)(Wt + (f4 * 4 + 1) * F_OUT + c * 4);
        const float4 w2 = *(const float4*)(Wt + (f4 * 4 + 2) * F_OUT + c * 4);
        const float4 w3 = *(const float4*)(Wt + (f4 * 4 + 3) * F_OUT + c * 4);
        oacc.x += inq.x * w0.x; oacc.y += inq.x * w0.y; oacc.z += inq.x * w0.z; oacc.w += inq.x * w0.w;
        oacc.x += inq.y * w1.x; oacc.y += inq.y * w1.y; oacc.z += inq.y * w1.z; oacc.w += inq.y * w1.w;
        oacc.x += inq.z * w2.x; oacc.y += inq.z * w2.y; oacc.z += inq.z * w2.z; oacc.w += inq.z * w2.w;
        oacc.x += inq.w * w3.x; oacc.y += inq.w * w3.y; oacc.z += inq.w * w3.z; oacc.w += inq.w * w3.w;
    }

    *(float4*)(out + ((size_t)b * N_NODES + n) * F_OUT + c * 4) = oacc;
}

extern "C" void kernel_launch(void* const* d_in, const int* in_sizes, int n_in,
                              void* d_out, int out_size, void* d_ws, size_t ws_size,
                              hipStream_t stream) {
    const float* x  = (const float*)d_in[0];
    const float* Wl = (const float*)d_in[1];
    const float* bl = (const float*)d_in[2];
    const float* Wr = (const float*)d_in[3];
    const void*  ei = d_in[4];
    float* out = (float*)d_out;
    char* ws = (char*)d_ws;

    if (ws_size >= (size_t)WS2_NEED + 1024) {
        int*            flag = (int*)(ws + WS2_FLAG);
        unsigned short* Wt   = (unsigned short*)(ws + WS2_WT);
        int*            deg  = (int*)(ws + WS2_DEG);
        int*            rowp = (int*)(ws + WS2_ROW);
        int*            cur  = (int*)(ws + WS2_CUR);
        int*            col  = (int*)(ws + WS2_COL);
        uint2*          xh2  = (uint2*)(ws + WS2_XH);

        hipMemsetAsync(ws + WS2_DEG, 0, WS2_COL - WS2_DEG, stream);
        detect_i64_kernel<<<1, 256, 0, stream>>>(ei, flag);
        make_wt_bf16<<<128, 256, 0, stream>>>(Wl, Wr, Wt);
        hist_kernel<<<(N_EDGES + 255) / 256, 256, 0, stream>>>(ei, flag, deg);
        scan_kernel<<<1, 1024, 0, stream>>>(deg, rowp);
        scatter_kernel<<<(N_EDGES + 255) / 256, 256, 0, stream>>>(ei, flag, rowp, cur, col);
        convert_kernel<<<(NROWS * 32) / 256, 256, 0, stream>>>(x, xh2);
        sage_fused2<<<N_NODES / 2, 256, 0, stream>>>(xh2, rowp, col, Wt, bl, out);
    } else {
        int*   flag      = (int*)(ws + WS_FLAG_OFF);
        float* Wt        = (float*)(ws + WS_WT_OFF);
        int*   deg       = (int*)(ws + WS_DEG_OFF);
        int*   row_start = (int*)(ws + WS_ROW_OFF);
        int*   cursor    = (int*)(ws + WS_CUR_OFF);
        int*   col       = (int*)(ws + WS_COL_OFF);

        hipMemsetAsync(d_ws, 0, WS_TOTAL, stream);
        detect_i64_kernel<<<1, 256, 0, stream>>>(ei, flag);
        transpose_w_kernel<<<(256 * 128) / 256, 256, 0, stream>>>(Wl, Wr, Wt);
        hist_kernel<<<(N_EDGES + 255) / 256, 256, 0, stream>>>(ei, flag, deg);
        scan_kernel<<<1, 1024, 0, stream>>>(deg, row_start);
        scatter_kernel<<<(N_EDGES + 255) / 256, 256, 0, stream>>>(ei, flag, row_start, cursor, col);
        sage_fused_kernel<<<N_NODES, 256, 0, stream>>>(x, bl, Wt, row_start, col, out);
    }
}